// Round 7
// baseline (260.184 us; speedup 1.0000x reference)
//
#include <hip/hip_runtime.h>
#include <hip/hip_bf16.h>
#include <math.h>

// Dims fixed by setup_inputs(): B=16, S=2048, D=1024, H=16, hd=64, P=8,
// cls=1, pma=8, recent=64, T=73.

#define Bn 16
#define Sn 2048
#define Dn 1024
#define Hn 16
#define Pn 8
#define Tn 73
#define RECn 64

typedef __attribute__((ext_vector_type(8))) short short8;
typedef __attribute__((ext_vector_type(4))) float f32x4;

__device__ __forceinline__ short f2bf(float x) {
    union { __hip_bfloat16 h; short s; } u;
    u.h = __float2bfloat16(x);   // native v_cvt, RNE
    return u.s;
}

// ---------------------------------------------------------------- mask dtype detect
__global__ void detect_mask_kernel(const unsigned char* __restrict__ raw,
                                   int* __restrict__ flag) {
    __shared__ int any;
    if (threadIdx.x == 0) any = 0;
    __syncthreads();
    const uint4* r4 = (const uint4*)raw;
    int local = 0;
    for (int i = threadIdx.x; i < (Bn * Sn) / 16; i += blockDim.x) {
        uint4 w = r4[i];
        if ((w.x & 0xFFFFFF00u) | (w.y & 0xFFFFFF00u) |
            (w.z & 0xFFFFFF00u) | (w.w & 0xFFFFFF00u)) local = 1;
    }
    if (local) any = 1; // benign race
    __syncthreads();
    if (threadIdx.x == 0) *flag = any;
}

__global__ void canon_mask_kernel(const void* __restrict__ raw,
                                  const int* __restrict__ flag,
                                  unsigned char* __restrict__ canon) {
    int i = blockIdx.x * blockDim.x + threadIdx.x;
    if (i >= Bn * Sn) return;
    unsigned char v;
    if (*flag)
        v = ((const unsigned char*)raw)[i] ? 1 : 0;
    else
        v = ((const int*)raw)[i] ? 1 : 0;
    canon[i] = v;
}

// ---------------------------------------------------------------- prep
__global__ void prep_kernel(const unsigned char* __restrict__ valid,
                            int* __restrict__ totals, int* __restrict__ rsrc,
                            float* __restrict__ maskf) {
    int b = blockIdx.x, t = threadIdx.x;
    const int SP = Sn - 1; // 2047
    __shared__ int lc[256];
    if (t < RECn) rsrc[b * RECn + t] = -1;

    int base = t * 8;
    unsigned char m[8];
    int cnt = 0;
#pragma unroll
    for (int i = 0; i < 8; i++) {
        int idx = base + i;
        m[i] = (idx < SP) ? valid[(size_t)b * Sn + 1 + idx] : (unsigned char)0;
        cnt += m[i] ? 1 : 0;
    }
    lc[t] = cnt;
    __syncthreads();
    for (int off = 1; off < 256; off <<= 1) {
        int add = (t >= off) ? lc[t - off] : 0;
        __syncthreads();
        lc[t] += add;
        __syncthreads();
    }
    int total = lc[255];
    int run = lc[t] - cnt; // exclusive prefix
#pragma unroll
    for (int i = 0; i < 8; i++) {
        if (m[i]) {
            run++;
            int rank = total - run;
            if (rank < RECn) rsrc[b * RECn + (RECn - 1 - rank)] = base + i + 1;
        }
    }
    if (t == 0) totals[b] = total;
    if (t < Tn) {
        float mv;
        if (t == 0) mv = valid[(size_t)b * Sn] ? 1.0f : 0.0f;
        else if (t < 1 + Pn) mv = 1.0f;
        else mv = ((t - 9) >= RECn - total) ? 1.0f : 0.0f;
        maskf[b * Tn + t] = mv;
    }
}

// ---------------------------------------------------------------- q = queries @ Wq^T + bq
__global__ void q_kernel(const float* __restrict__ queries,
                         const float* __restrict__ in_w,
                         const float* __restrict__ in_b,
                         float* __restrict__ q) {
    int wid = (blockIdx.x * blockDim.x + threadIdx.x) >> 6;
    int lane = threadIdx.x & 63;
    if (wid >= Pn * Dn) return;
    int p = wid >> 10, j = wid & 1023;
    float acc = 0.0f;
    for (int c = lane; c < Dn; c += 64)
        acc += queries[p * Dn + c] * in_w[(size_t)j * Dn + c];
#pragma unroll
    for (int off = 32; off > 0; off >>= 1) acc += __shfl_down(acc, off);
    if (lane == 0) q[wid] = acc + in_b[j];
}

// ---------------------------------------------------------------- A_bf[h*8+p,c] = bf16((q_h[p] . Wk_h[:,c]) / 8) ; c0
__global__ void A_kernel(const float* __restrict__ q,
                         const float* __restrict__ in_w,
                         const float* __restrict__ in_b,
                         short* __restrict__ Amat_bf, float* __restrict__ c0) {
    int h = blockIdx.x, cblk = blockIdx.y;
    int c = cblk * 256 + threadIdx.x;
    __shared__ float qs[8][64];
    for (int i = threadIdx.x; i < 512; i += 256) {
        int p = i >> 6, d = i & 63;
        qs[p][d] = q[p * Dn + h * 64 + d];
    }
    __syncthreads();
    float acc[8] = {};
#pragma unroll 8
    for (int d = 0; d < 64; d++) {
        float w = in_w[(size_t)(Dn + h * 64 + d) * Dn + c];
#pragma unroll
        for (int p = 0; p < 8; p++) acc[p] = fmaf(qs[p][d], w, acc[p]);
    }
#pragma unroll
    for (int p = 0; p < 8; p++)
        Amat_bf[(size_t)(h * 8 + p) * Dn + c] = f2bf(acc[p] * 0.125f);
    if (cblk == 0 && threadIdx.x < 8) {
        int p = threadIdx.x;
        float a = 0.0f;
        for (int d = 0; d < 64; d++) a += qs[p][d] * in_b[Dn + h * 64 + d];
        c0[h * 8 + p] = a * 0.125f;
    }
}

// ---------------------------------------------------------------- f32 -> bf16 elementwise (weights)
__global__ void wcvt_kernel(const float* __restrict__ w, short* __restrict__ wbf, int n) {
    int i = (blockIdx.x * blockDim.x + threadIdx.x) * 8;
    if (i >= n) return;
    f32x4 x0 = *(const f32x4*)(w + i);
    f32x4 x1 = *(const f32x4*)(w + i + 4);
    short8 o;
#pragma unroll
    for (int j = 0; j < 4; j++) { o[j] = f2bf(x0[j]); o[j + 4] = f2bf(x1[j]); }
    *(short8*)(wbf + i) = o;
}

// ---------------------------------------------------------------- scores[b,hp,s] = hidden[b,s,:]@A[hp,:] + c0 (MFMA bf16), masked
// 1024 blocks x 256 threads (4 waves). Block owns 32 s-rows; wave w owns
// rows (w>>1)*16 and hp half (w&1)*64. Amat K-chunks staged in
// double-buffered LDS; hidden prefetched 2 chunks ahead in regs.
__global__ __launch_bounds__(256) void scores_mfma(const float* __restrict__ hidden,
                                                   const short* __restrict__ Amat_bf,
                                                   const float* __restrict__ c0,
                                                   const unsigned char* __restrict__ valid,
                                                   float* __restrict__ scores) {
    int tid = threadIdx.x, wave = tid >> 6, lane = tid & 63;
    int l15 = lane & 15, koff = (lane >> 4) * 8;
    int mrow0 = blockIdx.x * 32 + (wave >> 1) * 16;
    int hpbase = (wave & 1) * 64;
    int b = mrow0 >> 11, s_base = mrow0 & 2047;

    __shared__ short Ab[2][128][40];          // [buf][hp][k] pitch 80B
    int shp = tid >> 1, skp = (tid & 1) * 16; // staging: thread -> (hp, k-half)
    const short* aglob = Amat_bf + (size_t)shp * Dn + skp;
    const float* hptr = hidden + (size_t)(mrow0 + l15) * Dn + koff;

    f32x4 acc[4] = {};
    // prologue: stage chunk 0 directly; prefetch hidden chunks 0,1
    {
        short8 s0 = *(const short8*)(aglob);
        short8 s1 = *(const short8*)(aglob + 8);
        *(short8*)(&Ab[0][shp][skp]) = s0;
        *(short8*)(&Ab[0][shp][skp + 8]) = s1;
    }
    f32x4 ha = *(const f32x4*)(hptr);
    f32x4 hb = *(const f32x4*)(hptr + 4);
    f32x4 ha1 = *(const f32x4*)(hptr + 32);
    f32x4 hb1 = *(const f32x4*)(hptr + 36);

    for (int ic = 0; ic < 32; ic++) {
        int cur = ic & 1;
        short8 nA0 = {}, nA1 = {};
        f32x4 nh0 = {}, nh1 = {};
        if (ic + 1 < 32) {
            nA0 = *(const short8*)(aglob + (ic + 1) * 32);
            nA1 = *(const short8*)(aglob + (ic + 1) * 32 + 8);
        }
        if (ic + 2 < 32) {
            nh0 = *(const f32x4*)(hptr + (ic + 2) * 32);
            nh1 = *(const f32x4*)(hptr + (ic + 2) * 32 + 4);
        }
        __syncthreads();                      // buf[cur] writes visible
        short8 av;
#pragma unroll
        for (int i = 0; i < 4; i++) { av[i] = f2bf(ha[i]); av[i + 4] = f2bf(hb[i]); }
#pragma unroll
        for (int nt = 0; nt < 4; nt++) {
            short8 bv = *(const short8*)(&Ab[cur][hpbase + nt * 16 + l15][koff]);
            acc[nt] = __builtin_amdgcn_mfma_f32_16x16x32_bf16(av, bv, acc[nt], 0, 0, 0);
        }
        if (ic + 1 < 32) {
            *(short8*)(&Ab[cur ^ 1][shp][skp]) = nA0;
            *(short8*)(&Ab[cur ^ 1][shp][skp + 8]) = nA1;
        }
        ha = ha1; hb = hb1; ha1 = nh0; hb1 = nh1;
    }
    // epilogue: C/D layout col=lane&15 (hp within tile), row=(lane>>4)*4+reg (s)
    int srow = s_base + (lane >> 4) * 4;
    const unsigned char* vptr = valid + (size_t)b * Sn + srow;
    bool ok0 = vptr[0] != 0, ok1 = vptr[1] != 0, ok2 = vptr[2] != 0, ok3 = vptr[3] != 0;
#pragma unroll
    for (int nt = 0; nt < 4; nt++) {
        int hp = hpbase + nt * 16 + l15;
        float cc = c0[hp];
        f32x4 st;
        st[0] = ok0 ? acc[nt][0] + cc : -1.0e9f;
        st[1] = ok1 ? acc[nt][1] + cc : -1.0e9f;
        st[2] = ok2 ? acc[nt][2] + cc : -1.0e9f;
        st[3] = ok3 ? acc[nt][3] + cc : -1.0e9f;
        *(f32x4*)(scores + (size_t)(b * 128 + hp) * Sn + srow) = st;
    }
}

// ---------------------------------------------------------------- softmax over s; writes bf16 attn
__global__ __launch_bounds__(256) void softmax_kernel(const float* __restrict__ scores,
                                                      short* __restrict__ attn_bf) {
    const float* row = scores + (size_t)blockIdx.x * Sn;
    short* orow = attn_bf + (size_t)blockIdx.x * Sn;
    int t = threadIdx.x;
    __shared__ float red[256];
    f32x4 v0 = *(const f32x4*)(row + t * 8);
    f32x4 v1 = *(const f32x4*)(row + t * 8 + 4);
    float mx = -1.0e30f;
#pragma unroll
    for (int i = 0; i < 4; i++) { mx = fmaxf(mx, v0[i]); mx = fmaxf(mx, v1[i]); }
    red[t] = mx;
    __syncthreads();
    for (int off = 128; off > 0; off >>= 1) {
        if (t < off) red[t] = fmaxf(red[t], red[t + off]);
        __syncthreads();
    }
    mx = red[0];
    __syncthreads();
    float e[8];
    float sum = 0.0f;
#pragma unroll
    for (int i = 0; i < 4; i++) {
        e[i] = expf(v0[i] - mx); sum += e[i];
        e[i + 4] = expf(v1[i] - mx); sum += e[i + 4];
    }
    red[t] = sum;
    __syncthreads();
    for (int off = 128; off > 0; off >>= 1) {
        if (t < off) red[t] += red[t + off];
        __syncthreads();
    }
    float inv = 1.0f / red[0];
    short8 o;
#pragma unroll
    for (int i = 0; i < 8; i++) o[i] = f2bf(e[i] * inv);
    *(short8*)(orow + t * 8) = o;
}

// ---------------------------------------------------------------- U partials: Up[b,hp,c] = sum_{s in z-chunk} attn[b,hp,s]*hidden[b,s,c]
// grid (8 n-tiles, 16 b, 4 z) x 512 threads (8 waves). Tile 128(hp) x 128(c).
// hidden staged through LDS transposed to [c][k] bf16 (pitch 40), dbuf.
__global__ __launch_bounds__(512) void U_mfma(const short* __restrict__ attn_bf,
                                              const float* __restrict__ hidden,
                                              float* __restrict__ Up0,
                                              float* __restrict__ Up1,
                                              float* __restrict__ Up2,
                                              float* __restrict__ Up3) {
    int b = blockIdx.y, n0 = blockIdx.x * 128, z = blockIdx.z;
    int zbase = z * 512;
    float* Up = (z == 0) ? Up0 : (z == 1) ? Up1 : (z == 2) ? Up2 : Up3;

    int tid = threadIdx.x, wave = tid >> 6, lane = tid & 63;
    int l15 = lane & 15;
    __shared__ short ldsB[2][128][40];
    int kr = tid & 31, nc = (tid >> 5) * 8;   // staging: (k=kr, c=nc..nc+7)
    int koff = (lane >> 4) * 8;
    f32x4 acc[8] = {};
    const short* aBase = attn_bf + ((size_t)b * 128 + wave * 16 + l15) * Sn + zbase + koff;
    const float* hBase = hidden + ((size_t)b * Sn + zbase + kr) * Dn + n0 + nc;

    const int nk = 16;                        // 512 / 32
    f32x4 h0 = *(const f32x4*)(hBase);
    f32x4 h1 = *(const f32x4*)(hBase + 4);
#pragma unroll
    for (int i = 0; i < 4; i++) {
        ldsB[0][nc + i][kr] = f2bf(h0[i]);
        ldsB[0][nc + 4 + i][kr] = f2bf(h1[i]);
    }
    short8 av = *(const short8*)(aBase);

    for (int ic = 0; ic < nk; ic++) {
        int cur = ic & 1;
        bool more = (ic + 1 < nk);
        f32x4 hn0, hn1;
        short8 avn;
        if (more) {
            hn0 = *(const f32x4*)(hBase + (size_t)(ic + 1) * 32 * Dn);
            hn1 = *(const f32x4*)(hBase + (size_t)(ic + 1) * 32 * Dn + 4);
            avn = *(const short8*)(aBase + (ic + 1) * 32);
        }
        __syncthreads();                      // buf[cur] writes visible
#pragma unroll
        for (int nf = 0; nf < 8; nf++) {
            short8 bv = *(const short8*)(&ldsB[cur][nf * 16 + l15][koff]);
            acc[nf] = __builtin_amdgcn_mfma_f32_16x16x32_bf16(av, bv, acc[nf], 0, 0, 0);
        }
        if (more) {
#pragma unroll
            for (int i = 0; i < 4; i++) {
                ldsB[cur ^ 1][nc + i][kr] = f2bf(hn0[i]);
                ldsB[cur ^ 1][nc + 4 + i][kr] = f2bf(hn1[i]);
            }
            av = avn;
        }
    }
    int hp = wave * 16 + (lane >> 4) * 4;
#pragma unroll
    for (int nf = 0; nf < 8; nf++) {
        int c = n0 + nf * 16 + l15;
        float* up = Up + (size_t)(b * 128 + hp) * Dn + c;
#pragma unroll
        for (int r = 0; r < 4; r++) up[(size_t)r * Dn] = acc[nf][r];
    }
}

// ---------------------------------------------------------------- ctx[bp, h*64+d] = (sum Up)[b,h*8+p,:] . Wv[h*64+d,:] + bv  (MFMA)
__global__ __launch_bounds__(64) void ctx_mfma(const float* __restrict__ Up0,
                                               const float* __restrict__ Up1,
                                               const float* __restrict__ Up2,
                                               const float* __restrict__ Up3,
                                               const float* __restrict__ in_w,
                                               const float* __restrict__ in_b,
                                               float* __restrict__ ctx) {
    int bh = blockIdx.x, b = bh >> 4, h = bh & 15;
    int lane = threadIdx.x & 63, l15 = lane & 15, koff = (lane >> 4) * 8;
    int p = l15 & 7;
    size_t uoff = ((size_t)b * 128 + h * 8 + p) * Dn + koff;
    const float* wv = in_w + (size_t)(2 * Dn + h * 64 + l15) * Dn + koff;
    f32x4 acc[4] = {};
    for (int k0 = 0; k0 < Dn; k0 += 32) {
        f32x4 a0 = *(const f32x4*)(Up0 + uoff + k0);
        f32x4 a1 = *(const f32x4*)(Up0 + uoff + k0 + 4);
        f32x4 b0 = *(const f32x4*)(Up1 + uoff + k0);
        f32x4 b1 = *(const f32x4*)(Up1 + uoff + k0 + 4);
        f32x4 d0 = *(const f32x4*)(Up2 + uoff + k0);
        f32x4 d1 = *(const f32x4*)(Up2 + uoff + k0 + 4);
        f32x4 e0 = *(const f32x4*)(Up3 + uoff + k0);
        f32x4 e1 = *(const f32x4*)(Up3 + uoff + k0 + 4);
        short8 av;
#pragma unroll
        for (int i = 0; i < 4; i++) {
            av[i] = f2bf((a0[i] + b0[i]) + (d0[i] + e0[i]));
            av[i + 4] = f2bf((a1[i] + b1[i]) + (d1[i] + e1[i]));
        }
#pragma unroll
        for (int nt = 0; nt < 4; nt++) {
            f32x4 w0 = *(const f32x4*)(wv + (size_t)nt * 16 * Dn + k0);
            f32x4 w1 = *(const f32x4*)(wv + (size_t)nt * 16 * Dn + k0 + 4);
            short8 bv;
#pragma unroll
            for (int i = 0; i < 4; i++) { bv[i] = f2bf(w0[i]); bv[i + 4] = f2bf(w1[i]); }
            acc[nt] = __builtin_amdgcn_mfma_f32_16x16x32_bf16(av, bv, acc[nt], 0, 0, 0);
        }
    }
    if (lane < 32) {                          // rows 0-7 valid (p)
        int prow = (lane >> 4) * 4;
#pragma unroll
        for (int nt = 0; nt < 4; nt++) {
            int d = h * 64 + nt * 16 + l15;
            float bias = in_b[2 * Dn + d];
#pragma unroll
            for (int r = 0; r < 4; r++)
                ctx[(size_t)(b * 8 + prow + r) * Dn + d] = acc[nt][r] + bias;
        }
    }
}

// ---------------------------------------------------------------- pooled = ctx @ out_w^T + out_b (MFMA, f32 operands cvt in-reg)
__global__ __launch_bounds__(256) void pooled_mfma(const float* __restrict__ A,
                                                   const float* __restrict__ B,
                                                   const float* __restrict__ bias,
                                                   float* __restrict__ C, int M) {
    int wave = threadIdx.x >> 6, lane = threadIdx.x & 63;
    int l15 = lane & 15, koff = (lane >> 4) * 8;
    int m0 = blockIdx.x * 64 + (wave >> 1) * 32;
    int n0 = blockIdx.y * 64 + (wave & 1) * 32;
    f32x4 acc[2][2] = {};
    int ra0 = min(m0 + l15, M - 1);
    int ra1 = min(m0 + 16 + l15, M - 1);
    const float* a0p = A + (size_t)ra0 * Dn + koff;
    const float* a1p = A + (size_t)ra1 * Dn + koff;
    const float* b0p = B + (size_t)(n0 + l15) * Dn + koff;
    const float* b1p = B + (size_t)(n0 + 16 + l15) * Dn + koff;
    for (int k0 = 0; k0 < Dn; k0 += 32) {
        short8 av0, av1, bv0, bv1;
        f32x4 x, y;
        x = *(const f32x4*)(a0p + k0); y = *(const f32x4*)(a0p + k0 + 4);
#pragma unroll
        for (int i = 0; i < 4; i++) { av0[i] = f2bf(x[i]); av0[i + 4] = f2bf(y[i]); }
        x = *(const f32x4*)(a1p + k0); y = *(const f32x4*)(a1p + k0 + 4);
#pragma unroll
        for (int i = 0; i < 4; i++) { av1[i] = f2bf(x[i]); av1[i + 4] = f2bf(y[i]); }
        x = *(const f32x4*)(b0p + k0); y = *(const f32x4*)(b0p + k0 + 4);
#pragma unroll
        for (int i = 0; i < 4; i++) { bv0[i] = f2bf(x[i]); bv0[i + 4] = f2bf(y[i]); }
        x = *(const f32x4*)(b1p + k0); y = *(const f32x4*)(b1p + k0 + 4);
#pragma unroll
        for (int i = 0; i < 4; i++) { bv1[i] = f2bf(x[i]); bv1[i + 4] = f2bf(y[i]); }
        acc[0][0] = __builtin_amdgcn_mfma_f32_16x16x32_bf16(av0, bv0, acc[0][0], 0, 0, 0);
        acc[0][1] = __builtin_amdgcn_mfma_f32_16x16x32_bf16(av0, bv1, acc[0][1], 0, 0, 0);
        acc[1][0] = __builtin_amdgcn_mfma_f32_16x16x32_bf16(av1, bv0, acc[1][0], 0, 0, 0);
        acc[1][1] = __builtin_amdgcn_mfma_f32_16x16x32_bf16(av1, bv1, acc[1][1], 0, 0, 0);
    }
#pragma unroll
    for (int mf = 0; mf < 2; mf++) {
        int row0 = m0 + mf * 16 + (lane >> 4) * 4;
#pragma unroll
        for (int nf = 0; nf < 2; nf++) {
            int col = n0 + nf * 16 + l15;
            float bval = bias[col];
#pragma unroll
            for (int r = 0; r < 4; r++) {
                int row = row0 + r;
                if (row < M) C[(size_t)row * Dn + col] = acc[mf][nf][r] + bval;
            }
        }
    }
}

// ---------------------------------------------------------------- bf16 MFMA GEMM: C[M,1024] = A_bf[M,1024] @ B_bf[1024,1024]^T + bias
__global__ __launch_bounds__(256) void wgemm_mfma(const short* __restrict__ Abf,
                                                  const short* __restrict__ Bbf,
                                                  const float* __restrict__ bias,
                                                  float* __restrict__ C, int M) {
    int wave = threadIdx.x >> 6, lane = threadIdx.x & 63;
    int m0 = blockIdx.x * 64 + (wave >> 1) * 32;
    int n0 = blockIdx.y * 64 + (wave & 1) * 32;
    int koff = (lane >> 4) * 8;
    f32x4 acc[2][2] = {};
    int ra0 = min(m0 + (lane & 15), M - 1);
    int ra1 = min(m0 + 16 + (lane & 15), M - 1);
    const short* a0p = Abf + (size_t)ra0 * Dn + koff;
    const short* a1p = Abf + (size_t)ra1 * Dn + koff;
    const short* b0p = Bbf + (size_t)(n0 + (lane & 15)) * Dn + koff;
    const short* b1p = Bbf + (size_t)(n0 + 16 + (lane & 15)) * Dn + koff;
    for (int k0 = 0; k0 < Dn; k0 += 32) {
        short8 av0 = *(const short8*)(a0p + k0);
        short8 av1 = *(const short8*)(a1p + k0);
        short8 bv0 = *(const short8*)(b0p + k0);
        short8 bv1 = *(const short8*)(b1p + k0);
        acc[0][0] = __builtin_amdgcn_mfma_f32_16x16x32_bf16(av0, bv0, acc[0][0], 0, 0, 0);
        acc[0][1] = __builtin_amdgcn_mfma_f32_16x16x32_bf16(av0, bv1, acc[0][1], 0, 0, 0);
        acc[1][0] = __builtin_amdgcn_mfma_f32_16x16x32_bf16(av1, bv0, acc[1][0], 0, 0, 0);
        acc[1][1] = __builtin_amdgcn_mfma_f32_16x16x32_bf16(av1, bv1, acc[1][1], 0, 0, 0);
    }
#pragma unroll
    for (int mf = 0; mf < 2; mf++) {
        int row0 = m0 + mf * 16 + (lane >> 4) * 4;
#pragma unroll
        for (int nf = 0; nf < 2; nf++) {
            int col = n0 + nf * 16 + (lane & 15);
            float bval = bias[col];
#pragma unroll
            for (int r = 0; r < 4; r++) {
                int row = row0 + r;
                if (row < M) C[(size_t)row * Dn + col] = acc[mf][nf][r] + bval;
            }
        }
    }
}

// ---------------------------------------------------------------- block sum helper
__device__ __forceinline__ float block_sum(float v, float* red) {
    int tid = threadIdx.x;
    red[tid] = v;
    __syncthreads();
    for (int off = 128; off > 0; off >>= 1) {
        if (tid < off) red[tid] += red[tid + off];
        __syncthreads();
    }
    float r = red[0];
    __syncthreads();
    return r;
}

// ---------------------------------------------------------------- build summary row + LN_pma + LN_v / LN_g (bf16 out)
__global__ void summary_ln_kernel(const float* __restrict__ hidden,
                                  const float* __restrict__ queries,
                                  const float* __restrict__ pooled,
                                  const int* __restrict__ rsrc,
                                  const float* __restrict__ gpma, const float* __restrict__ bpma,
                                  const float* __restrict__ gv, const float* __restrict__ bv,
                                  const float* __restrict__ gg, const float* __restrict__ bg,
                                  short* __restrict__ lnv, short* __restrict__ lng) {
    __shared__ float red[256];
    int b = blockIdx.x, t = blockIdx.y, tid = threadIdx.x;
    float x[4];
    if (t == 0) {
#pragma unroll
        for (int i = 0; i < 4; i++)
            x[i] = hidden[(size_t)b * Sn * Dn + tid + i * 256];
    } else if (t < 1 + Pn) {
        int p = t - 1;
#pragma unroll
        for (int i = 0; i < 4; i++) {
            int c = tid + i * 256;
            x[i] = queries[p * Dn + c] + pooled[((size_t)b * Pn + p) * Dn + c];
        }
    } else {
        int src = rsrc[b * RECn + (t - 9)];
        if (src >= 0) {
#pragma unroll
            for (int i = 0; i < 4; i++)
                x[i] = hidden[((size_t)b * Sn + src) * Dn + tid + i * 256];
        } else {
#pragma unroll
            for (int i = 0; i < 4; i++) x[i] = 0.0f;
        }
    }
    if (t >= 1 && t < 1 + Pn) {
        float mu = block_sum(x[0] + x[1] + x[2] + x[3], red) * (1.0f / Dn);
        float d2 = 0.0f;
#pragma unroll
        for (int i = 0; i < 4; i++) { float d = x[i] - mu; d2 += d * d; }
        float inv = rsqrtf(block_sum(d2, red) * (1.0f / Dn) + 1e-5f);
#pragma unroll
        for (int i = 0; i < 4; i++) {
            int c = tid + i * 256;
            x[i] = (x[i] - mu) * inv * gpma[c] + bpma[c];
        }
    }
    float mu = block_sum(x[0] + x[1] + x[2] + x[3], red) * (1.0f / Dn);
    float d2 = 0.0f;
#pragma unroll
    for (int i = 0; i < 4; i++) { float d = x[i] - mu; d2 += d * d; }
    float inv = rsqrtf(block_sum(d2, red) * (1.0f / Dn) + 1e-5f);
    size_t row = (size_t)(b * Tn + t) * Dn;
#pragma unroll
    for (int i = 0; i < 4; i++) {
        int c = tid + i * 256;
        float xh = (x[i] - mu) * inv;
        lnv[row + c] = f2bf(xh * gv[c] + bv[c]);
        lng[row + c] = f2bf(xh * gg[c] + bg[c]);
    }
}

// ---------------------------------------------------------------- gated = sigmoid(c2) * silu(c1) * mask
__global__ void gated_kernel(const float* __restrict__ c1, const float* __restrict__ c2,
                             const float* __restrict__ maskf, float* __restrict__ out) {
    int gi = blockIdx.x * blockDim.x + threadIdx.x;
    int row = gi >> 10;
    float m = maskf[row];
    float a = c1[gi], g = c2[gi];
    float sv = a / (1.0f + expf(-a));
    float sg = 1.0f / (1.0f + expf(-g));
    out[gi] = sg * sv * m;
}

// ================================================================ launch
extern "C" void kernel_launch(void* const* d_in, const int* in_sizes, int n_in,
                              void* d_out, int out_size, void* d_ws, size_t ws_size,
                              hipStream_t stream) {
    const float* hidden = (const float*)d_in[0];
    const void* valid_raw = d_in[1];
    const float* queries = (const float*)d_in[2];
    const float* in_w = (const float*)d_in[3];
    const float* in_b = (const float*)d_in[4];
    const float* out_w = (const float*)d_in[5];
    const float* out_b = (const float*)d_in[6];
    const float* ln_pma_g = (const float*)d_in[7];
    const float* ln_pma_b = (const float*)d_in[8];
    const float* ln_v_g = (const float*)d_in[9];
    const float* ln_v_b = (const float*)d_in[10];
    const float* W_v = (const float*)d_in[11];
    const float* b_v = (const float*)d_in[12];
    const float* ln_g_g = (const float*)d_in[13];
    const float* ln_g_b = (const float*)d_in[14];
    const float* W_g = (const float*)d_in[15];
    const float* b_g = (const float*)d_in[16];

    float* ws = (float*)d_ws;
    float* out = (float*)d_out;

    // workspace layout (float offsets):
    float* SC      = ws;                         // scores f32: 4,194,304 f (dead after softmax)
    short* attn_bf = (short*)(ws + 4194304);     // 4,194,304 shorts (2,097,152 f)
    float* Up0     = ws + 6291456;               // 2,097,152 f
    float* Up1     = ws;                         // overlay in dead SC region
    float* Up2     = ws + 2097152;               // overlay in dead SC region
    float* Up3     = ws + 8388608;               // 2,097,152 f
    float* qbuf    = ws + 10485760;              // 8,192
    short* Amat_bf = (short*)(ws + 10493952);    // 65,536 f
    float* c0      = ws + 10559488;              // 256
    float* ctx     = ws + 10559744;              // 131,072
    float* pooled  = ws + 10690816;              // 131,072
    short* Wv_bf   = (short*)(ws + 10821888);    // 524,288 f
    short* Wg_bf   = (short*)(ws + 11346176);    // 524,288 f
    int*   ivals   = (int*)(ws + 11870464);
    int* totals = ivals;                         // 16
    int* rsrc = ivals + 16;                      // 1024
    int* flag = ivals + 16 + 1024;               // 16
    unsigned char* canon = (unsigned char*)(ivals + 16 + 1024 + 16); // 32768 B
    // post-ctx overlays in SC region (Up1/Up2 dead after ctx):
    short* lnv_bf = (short*)ws;                  // 598,016 f worth
    short* lng_bf = (short*)(ws + 622592);
    float* c1 = ws + 1245184;
    float* c2 = ws + 2441216;                    // ends 3,637,248 < 4,194,304 OK
    float* maskf = out + (size_t)Bn * Tn * Dn;

    const int M2 = Bn * Tn; // 1168

    detect_mask_kernel<<<1, 256, 0, stream>>>((const unsigned char*)valid_raw, flag);
    canon_mask_kernel<<<(Bn * Sn) / 256, 256, 0, stream>>>(valid_raw, flag, canon);
    prep_kernel<<<Bn, 256, 0, stream>>>(canon, totals, rsrc, maskf);
    q_kernel<<<(Pn * Dn) / 4, 256, 0, stream>>>(queries, in_w, in_b, qbuf);
    A_kernel<<<dim3(Hn, 4), 256, 0, stream>>>(qbuf, in_w, in_b, Amat_bf, c0);
    wcvt_kernel<<<512, 256, 0, stream>>>(W_v, Wv_bf, Dn * Dn);
    wcvt_kernel<<<512, 256, 0, stream>>>(W_g, Wg_bf, Dn * Dn);
    scores_mfma<<<(Bn * Sn) / 32, 256, 0, stream>>>(hidden, Amat_bf, c0, canon, SC);
    softmax_kernel<<<Bn * 128, 256, 0, stream>>>(SC, attn_bf);
    U_mfma<<<dim3(8, Bn, 4), 512, 0, stream>>>(attn_bf, hidden, Up0, Up1, Up2, Up3);
    ctx_mfma<<<Bn * Hn, 64, 0, stream>>>(Up0, Up1, Up2, Up3, in_w, in_b, ctx);
    pooled_mfma<<<dim3(2, 16), 256, 0, stream>>>(ctx, out_w, out_b, pooled, Bn * Pn);
    summary_ln_kernel<<<dim3(Bn, Tn), 256, 0, stream>>>(hidden, queries, pooled, rsrc,
                                                        ln_pma_g, ln_pma_b, ln_v_g, ln_v_b,
                                                        ln_g_g, ln_g_b, lnv_bf, lng_bf);
    wgemm_mfma<<<dim3((M2 + 63) / 64, 16), 256, 0, stream>>>(lnv_bf, Wv_bf, b_v, c1, M2);
    wgemm_mfma<<<dim3((M2 + 63) / 64, 16), 256, 0, stream>>>(lng_bf, Wg_bf, b_g, c2, M2);
    gated_kernel<<<(Bn * Tn * Dn) / 256, 256, 0, stream>>>(c1, c2, maskf, out);
}

// Round 8
// 249.212 us; speedup vs baseline: 1.0440x; 1.0440x over previous
//
#include <hip/hip_runtime.h>
#include <hip/hip_bf16.h>
#include <math.h>

// Dims fixed by setup_inputs(): B=16, S=2048, D=1024, H=16, hd=64, P=8,
// cls=1, pma=8, recent=64, T=73.

#define Bn 16
#define Sn 2048
#define Dn 1024
#define Hn 16
#define Pn 8
#define Tn 73
#define RECn 64

typedef __attribute__((ext_vector_type(8))) short short8;
typedef __attribute__((ext_vector_type(4))) float f32x4;

__device__ __forceinline__ short f2bf(float x) {
    union { __hip_bfloat16 h; short s; } u;
    u.h = __float2bfloat16(x);   // native v_cvt, RNE
    return u.s;
}

// XOR swizzle for 128-row x 512-short LDS tiles: spreads the 16B slot of
// row r across bank groups (2-way max on reads; +1-pad impossible at this
// size, swizzle is free). ks must be a multiple of 8 for short8 access.
__device__ __forceinline__ int swz(int row, int ks) {
    return row * 512 + (ks ^ ((row & 7) << 3));
}

// ---------------------------------------------------------------- mask dtype detect
__global__ void detect_mask_kernel(const unsigned char* __restrict__ raw,
                                   int* __restrict__ flag) {
    __shared__ int any;
    if (threadIdx.x == 0) any = 0;
    __syncthreads();
    const uint4* r4 = (const uint4*)raw;
    int local = 0;
    for (int i = threadIdx.x; i < (Bn * Sn) / 16; i += blockDim.x) {
        uint4 w = r4[i];
        if ((w.x & 0xFFFFFF00u) | (w.y & 0xFFFFFF00u) |
            (w.z & 0xFFFFFF00u) | (w.w & 0xFFFFFF00u)) local = 1;
    }
    if (local) any = 1; // benign race
    __syncthreads();
    if (threadIdx.x == 0) *flag = any;
}

__global__ void canon_mask_kernel(const void* __restrict__ raw,
                                  const int* __restrict__ flag,
                                  unsigned char* __restrict__ canon) {
    int i = blockIdx.x * blockDim.x + threadIdx.x;
    if (i >= Bn * Sn) return;
    unsigned char v;
    if (*flag)
        v = ((const unsigned char*)raw)[i] ? 1 : 0;
    else
        v = ((const int*)raw)[i] ? 1 : 0;
    canon[i] = v;
}

// ---------------------------------------------------------------- prep
__global__ void prep_kernel(const unsigned char* __restrict__ valid,
                            int* __restrict__ totals, int* __restrict__ rsrc,
                            float* __restrict__ maskf) {
    int b = blockIdx.x, t = threadIdx.x;
    const int SP = Sn - 1; // 2047
    __shared__ int lc[256];
    if (t < RECn) rsrc[b * RECn + t] = -1;

    int base = t * 8;
    unsigned char m[8];
    int cnt = 0;
#pragma unroll
    for (int i = 0; i < 8; i++) {
        int idx = base + i;
        m[i] = (idx < SP) ? valid[(size_t)b * Sn + 1 + idx] : (unsigned char)0;
        cnt += m[i] ? 1 : 0;
    }
    lc[t] = cnt;
    __syncthreads();
    for (int off = 1; off < 256; off <<= 1) {
        int add = (t >= off) ? lc[t - off] : 0;
        __syncthreads();
        lc[t] += add;
        __syncthreads();
    }
    int total = lc[255];
    int run = lc[t] - cnt; // exclusive prefix
#pragma unroll
    for (int i = 0; i < 8; i++) {
        if (m[i]) {
            run++;
            int rank = total - run;
            if (rank < RECn) rsrc[b * RECn + (RECn - 1 - rank)] = base + i + 1;
        }
    }
    if (t == 0) totals[b] = total;
    if (t < Tn) {
        float mv;
        if (t == 0) mv = valid[(size_t)b * Sn] ? 1.0f : 0.0f;
        else if (t < 1 + Pn) mv = 1.0f;
        else mv = ((t - 9) >= RECn - total) ? 1.0f : 0.0f;
        maskf[b * Tn + t] = mv;
    }
}

// ---------------------------------------------------------------- q = queries @ Wq^T + bq
__global__ void q_kernel(const float* __restrict__ queries,
                         const float* __restrict__ in_w,
                         const float* __restrict__ in_b,
                         float* __restrict__ q) {
    int wid = (blockIdx.x * blockDim.x + threadIdx.x) >> 6;
    int lane = threadIdx.x & 63;
    if (wid >= Pn * Dn) return;
    int p = wid >> 10, j = wid & 1023;
    float acc = 0.0f;
    for (int c = lane; c < Dn; c += 64)
        acc += queries[p * Dn + c] * in_w[(size_t)j * Dn + c];
#pragma unroll
    for (int off = 32; off > 0; off >>= 1) acc += __shfl_down(acc, off);
    if (lane == 0) q[wid] = acc + in_b[j];
}

// ---------------------------------------------------------------- A_bf[h*8+p,c] = bf16((q_h[p] . Wk_h[:,c]) / 8) ; c0
__global__ void A_kernel(const float* __restrict__ q,
                         const float* __restrict__ in_w,
                         const float* __restrict__ in_b,
                         short* __restrict__ Amat_bf, float* __restrict__ c0) {
    int h = blockIdx.x, cblk = blockIdx.y;
    int c = cblk * 256 + threadIdx.x;
    __shared__ float qs[8][64];
    for (int i = threadIdx.x; i < 512; i += 256) {
        int p = i >> 6, d = i & 63;
        qs[p][d] = q[p * Dn + h * 64 + d];
    }
    __syncthreads();
    float acc[8] = {};
#pragma unroll 8
    for (int d = 0; d < 64; d++) {
        float w = in_w[(size_t)(Dn + h * 64 + d) * Dn + c];
#pragma unroll
        for (int p = 0; p < 8; p++) acc[p] = fmaf(qs[p][d], w, acc[p]);
    }
#pragma unroll
    for (int p = 0; p < 8; p++)
        Amat_bf[(size_t)(h * 8 + p) * Dn + c] = f2bf(acc[p] * 0.125f);
    if (cblk == 0 && threadIdx.x < 8) {
        int p = threadIdx.x;
        float a = 0.0f;
        for (int d = 0; d < 64; d++) a += qs[p][d] * in_b[Dn + h * 64 + d];
        c0[h * 8 + p] = a * 0.125f;
    }
}

// ---------------------------------------------------------------- f32 -> bf16 elementwise (weights)
__global__ void wcvt_kernel(const float* __restrict__ w, short* __restrict__ wbf, int n) {
    int i = (blockIdx.x * blockDim.x + threadIdx.x) * 8;
    if (i >= n) return;
    f32x4 x0 = *(const f32x4*)(w + i);
    f32x4 x1 = *(const f32x4*)(w + i + 4);
    short8 o;
#pragma unroll
    for (int j = 0; j < 4; j++) { o[j] = f2bf(x0[j]); o[j + 4] = f2bf(x1[j]); }
    *(short8*)(wbf + i) = o;
}

// ---------------------------------------------------------------- scores partial (K-half):
// SCp[b,hp,s] = hidden[b,s,khalf:khalf+512] @ A[hp,khalf:khalf+512]^T
// grid (256 m-blocks, 2 khalf) x 512 threads (8 waves). Block = 128 s-rows x
// 128 hp. Amat K-half staged in 128KiB LDS ONCE (single barrier), then a
// barrier-free K-loop: hidden streams through regs (2-chunk prefetch, never
// drained by a barrier). c0/mask applied later in softmax.
__global__ __launch_bounds__(512) void scores_mfma(const float* __restrict__ hidden,
                                                   const short* __restrict__ Amat_bf,
                                                   float* __restrict__ SCp0,
                                                   float* __restrict__ SCp1) {
    __shared__ short Bsh[128 * 512];          // 128 hp x 512 k, swizzled
    int tid = threadIdx.x, wave = tid >> 6, lane = tid & 63;
    int l15 = lane & 15, q = lane >> 4;
    int kz = blockIdx.y, khalf = kz << 9;
    float* SCp = kz ? SCp1 : SCp0;
    int m0 = blockIdx.x * 128 + wave * 16;
    int b = m0 >> 11, s_base = m0 & 2047;

    // stage Amat[0..127][khalf..khalf+511] -> LDS (once)
    {
        int r = tid >> 2, k0 = (tid & 3) * 128;
        const short* src = Amat_bf + (size_t)r * Dn + khalf + k0;
#pragma unroll
        for (int j = 0; j < 16; j++) {
            short8 v = *(const short8*)(src + j * 8);
            *(short8*)(&Bsh[swz(r, k0 + j * 8)]) = v;
        }
    }
    __syncthreads();                          // the only barrier

    const float* aptr = hidden + (size_t)(m0 + l15) * Dn + khalf + q * 8;
    f32x4 acc[8] = {};
    f32x4 pa[2][2];
    pa[0][0] = *(const f32x4*)(aptr);       pa[0][1] = *(const f32x4*)(aptr + 4);
    pa[1][0] = *(const f32x4*)(aptr + 32);  pa[1][1] = *(const f32x4*)(aptr + 36);
#pragma unroll 4
    for (int ic = 0; ic < 16; ic++) {
        f32x4 c0r = pa[ic & 1][0], c1r = pa[ic & 1][1];
        if (ic + 2 < 16) {
            pa[ic & 1][0] = *(const f32x4*)(aptr + (ic + 2) * 32);
            pa[ic & 1][1] = *(const f32x4*)(aptr + (ic + 2) * 32 + 4);
        }
        short8 av;
#pragma unroll
        for (int i = 0; i < 4; i++) { av[i] = f2bf(c0r[i]); av[i + 4] = f2bf(c1r[i]); }
#pragma unroll
        for (int nt = 0; nt < 8; nt++) {
            short8 bv = *(const short8*)(&Bsh[swz(nt * 16 + l15, ic * 32 + q * 8)]);
            acc[nt] = __builtin_amdgcn_mfma_f32_16x16x32_bf16(av, bv, acc[nt], 0, 0, 0);
        }
    }
    // raw partial write: C/D layout col=lane&15 (hp), row=q*4+reg (s)
    int srow = s_base + q * 4;
#pragma unroll
    for (int nt = 0; nt < 8; nt++) {
        int hp = nt * 16 + l15;
        *(f32x4*)(SCp + (size_t)(b * 128 + hp) * Sn + srow) = acc[nt];
    }
}

// ---------------------------------------------------------------- softmax over s (sum of K-half partials + c0, masked); writes bf16 attn
__global__ __launch_bounds__(256) void softmax_kernel(const float* __restrict__ p0,
                                                      const float* __restrict__ p1,
                                                      const float* __restrict__ c0,
                                                      const unsigned char* __restrict__ valid,
                                                      short* __restrict__ attn_bf) {
    int rowid = blockIdx.x;                   // b*128 + hp
    int b = rowid >> 7, hp = rowid & 127;
    const float* r0 = p0 + (size_t)rowid * Sn;
    const float* r1 = p1 + (size_t)rowid * Sn;
    const unsigned char* vp = valid + (size_t)b * Sn;
    short* orow = attn_bf + (size_t)rowid * Sn;
    int t = threadIdx.x;
    float cc = c0[hp];
    __shared__ float red[256];
    f32x4 a0 = *(const f32x4*)(r0 + t * 8);
    f32x4 a1 = *(const f32x4*)(r0 + t * 8 + 4);
    f32x4 b0 = *(const f32x4*)(r1 + t * 8);
    f32x4 b1 = *(const f32x4*)(r1 + t * 8 + 4);
    float v[8];
#pragma unroll
    for (int i = 0; i < 4; i++) {
        v[i] = (vp[t * 8 + i] != 0) ? (a0[i] + b0[i] + cc) : -1.0e9f;
        v[i + 4] = (vp[t * 8 + 4 + i] != 0) ? (a1[i] + b1[i] + cc) : -1.0e9f;
    }
    float mx = -1.0e30f;
#pragma unroll
    for (int i = 0; i < 8; i++) mx = fmaxf(mx, v[i]);
    red[t] = mx;
    __syncthreads();
    for (int off = 128; off > 0; off >>= 1) {
        if (t < off) red[t] = fmaxf(red[t], red[t + off]);
        __syncthreads();
    }
    mx = red[0];
    __syncthreads();
    float sum = 0.0f;
#pragma unroll
    for (int i = 0; i < 8; i++) { v[i] = expf(v[i] - mx); sum += v[i]; }
    red[t] = sum;
    __syncthreads();
    for (int off = 128; off > 0; off >>= 1) {
        if (t < off) red[t] += red[t + off];
        __syncthreads();
    }
    float inv = 1.0f / red[0];
    short8 o;
#pragma unroll
    for (int i = 0; i < 8; i++) o[i] = f2bf(v[i] * inv);
    *(short8*)(orow + t * 8) = o;
}

// ---------------------------------------------------------------- U partials: Up[b,hp,c] = sum_{s in z-chunk} attn[b,hp,s]*hidden[b,s,c]
// grid (8 c-tiles, 16 b, 4 z) x 512 threads (8 waves). Hidden z-chunk staged
// TRANSPOSED ([c][s] bf16) in 128KiB LDS ONCE; attn (bf16) streams as the
// A-operand with 2-chunk prefetch, barrier-free main loop.
__global__ __launch_bounds__(512) void U_mfma(const short* __restrict__ attn_bf,
                                              const float* __restrict__ hidden,
                                              float* __restrict__ Up0,
                                              float* __restrict__ Up1,
                                              float* __restrict__ Up2,
                                              float* __restrict__ Up3) {
    __shared__ short Hs[128 * 512];           // 128 c x 512 s, swizzled
    int n0 = blockIdx.x * 128, b = blockIdx.y, z = blockIdx.z;
    int zbase = z * 512;
    float* Up = (z == 0) ? Up0 : (z == 1) ? Up1 : (z == 2) ? Up2 : Up3;
    int tid = threadIdx.x, wave = tid >> 6, lane = tid & 63;
    int l15 = lane & 15, q = lane >> 4;

    // stage: thread t owns s-row = tid; transpose-write 128 c values
    {
        const float* src = hidden + ((size_t)b * Sn + zbase + tid) * Dn + n0;
#pragma unroll 4
        for (int c = 0; c < 128; c += 8) {
            f32x4 x = *(const f32x4*)(src + c);
            f32x4 y = *(const f32x4*)(src + c + 4);
#pragma unroll
            for (int i = 0; i < 4; i++) {
                Hs[swz(c + i, 0) + ((tid ^ (((c + i) & 7) << 3)) - (0 ^ (((c + i) & 7) << 3)))] = f2bf(x[i]);
            }
#pragma unroll
            for (int i = 0; i < 4; i++) {
                Hs[(c + 4 + i) * 512 + (tid ^ (((c + 4 + i) & 7) << 3))] = f2bf(y[i]);
            }
        }
    }
    __syncthreads();                          // the only barrier

    const short* ap = attn_bf + ((size_t)b * 128 + wave * 16 + l15) * Sn + zbase + q * 8;
    f32x4 acc[8] = {};
    short8 pa[2];
    pa[0] = *(const short8*)(ap);
    pa[1] = *(const short8*)(ap + 32);
#pragma unroll 4
    for (int ic = 0; ic < 16; ic++) {
        short8 av = pa[ic & 1];
        if (ic + 2 < 16) pa[ic & 1] = *(const short8*)(ap + (ic + 2) * 32);
#pragma unroll
        for (int nf = 0; nf < 8; nf++) {
            short8 bv = *(const short8*)(&Hs[swz(nf * 16 + l15, ic * 32 + q * 8)]);
            acc[nf] = __builtin_amdgcn_mfma_f32_16x16x32_bf16(av, bv, acc[nf], 0, 0, 0);
        }
    }
    int hp = wave * 16 + q * 4;
#pragma unroll
    for (int nf = 0; nf < 8; nf++) {
        int c = n0 + nf * 16 + l15;
        float* up = Up + (size_t)(b * 128 + hp) * Dn + c;
#pragma unroll
        for (int r = 0; r < 4; r++) up[(size_t)r * Dn] = acc[nf][r];
    }
}

// ---------------------------------------------------------------- ctx[bp, h*64+d] = (sum Up)[b,h*8+p,:] . Wv[h*64+d,:] + bv  (MFMA)
__global__ __launch_bounds__(64) void ctx_mfma(const float* __restrict__ Up0,
                                               const float* __restrict__ Up1,
                                               const float* __restrict__ Up2,
                                               const float* __restrict__ Up3,
                                               const float* __restrict__ in_w,
                                               const float* __restrict__ in_b,
                                               float* __restrict__ ctx) {
    int bh = blockIdx.x, b = bh >> 4, h = bh & 15;
    int lane = threadIdx.x & 63, l15 = lane & 15, koff = (lane >> 4) * 8;
    int p = l15 & 7;
    size_t uoff = ((size_t)b * 128 + h * 8 + p) * Dn + koff;
    const float* wv = in_w + (size_t)(2 * Dn + h * 64 + l15) * Dn + koff;
    f32x4 acc[4] = {};
    for (int k0 = 0; k0 < Dn; k0 += 32) {
        f32x4 a0 = *(const f32x4*)(Up0 + uoff + k0);
        f32x4 a1 = *(const f32x4*)(Up0 + uoff + k0 + 4);
        f32x4 b0 = *(const f32x4*)(Up1 + uoff + k0);
        f32x4 b1 = *(const f32x4*)(Up1 + uoff + k0 + 4);
        f32x4 d0 = *(const f32x4*)(Up2 + uoff + k0);
        f32x4 d1 = *(const f32x4*)(Up2 + uoff + k0 + 4);
        f32x4 e0 = *(const f32x4*)(Up3 + uoff + k0);
        f32x4 e1 = *(const f32x4*)(Up3 + uoff + k0 + 4);
        short8 av;
#pragma unroll
        for (int i = 0; i < 4; i++) {
            av[i] = f2bf((a0[i] + b0[i]) + (d0[i] + e0[i]));
            av[i + 4] = f2bf((a1[i] + b1[i]) + (d1[i] + e1[i]));
        }
#pragma unroll
        for (int nt = 0; nt < 4; nt++) {
            f32x4 w0 = *(const f32x4*)(wv + (size_t)nt * 16 * Dn + k0);
            f32x4 w1 = *(const f32x4*)(wv + (size_t)nt * 16 * Dn + k0 + 4);
            short8 bv;
#pragma unroll
            for (int i = 0; i < 4; i++) { bv[i] = f2bf(w0[i]); bv[i + 4] = f2bf(w1[i]); }
            acc[nt] = __builtin_amdgcn_mfma_f32_16x16x32_bf16(av, bv, acc[nt], 0, 0, 0);
        }
    }
    if (lane < 32) {                          // rows 0-7 valid (p)
        int prow = (lane >> 4) * 4;
#pragma unroll
        for (int nt = 0; nt < 4; nt++) {
            int d = h * 64 + nt * 16 + l15;
            float bias = in_b[2 * Dn + d];
#pragma unroll
            for (int r = 0; r < 4; r++)
                ctx[(size_t)(b * 8 + prow + r) * Dn + d] = acc[nt][r] + bias;
        }
    }
}

// ---------------------------------------------------------------- pooled = ctx @ out_w^T + out_b (MFMA, f32 operands cvt in-reg)
__global__ __launch_bounds__(256) void pooled_mfma(const float* __restrict__ A,
                                                   const float* __restrict__ B,
                                                   const float* __restrict__ bias,
                                                   float* __restrict__ C, int M) {
    int wave = threadIdx.x >> 6, lane = threadIdx.x & 63;
    int l15 = lane & 15, koff = (lane >> 4) * 8;
    int m0 = blockIdx.x * 64 + (wave >> 1) * 32;
    int n0 = blockIdx.y * 64 + (wave & 1) * 32;
    f32x4 acc[2][2] = {};
    int ra0 = min(m0 + l15, M - 1);
    int ra1 = min(m0 + 16 + l15, M - 1);
    const float* a0p = A + (size_t)ra0 * Dn + koff;
    const float* a1p = A + (size_t)ra1 * Dn + koff;
    const float* b0p = B + (size_t)(n0 + l15) * Dn + koff;
    const float* b1p = B + (size_t)(n0 + 16 + l15) * Dn + koff;
    for (int k0 = 0; k0 < Dn; k0 += 32) {
        short8 av0, av1, bv0, bv1;
        f32x4 x, y;
        x = *(const f32x4*)(a0p + k0); y = *(const f32x4*)(a0p + k0 + 4);
#pragma unroll
        for (int i = 0; i < 4; i++) { av0[i] = f2bf(x[i]); av0[i + 4] = f2bf(y[i]); }
        x = *(const f32x4*)(a1p + k0); y = *(const f32x4*)(a1p + k0 + 4);
#pragma unroll
        for (int i = 0; i < 4; i++) { av1[i] = f2bf(x[i]); av1[i + 4] = f2bf(y[i]); }
        x = *(const f32x4*)(b0p + k0); y = *(const f32x4*)(b0p + k0 + 4);
#pragma unroll
        for (int i = 0; i < 4; i++) { bv0[i] = f2bf(x[i]); bv0[i + 4] = f2bf(y[i]); }
        x = *(const f32x4*)(b1p + k0); y = *(const f32x4*)(b1p + k0 + 4);
#pragma unroll
        for (int i = 0; i < 4; i++) { bv1[i] = f2bf(x[i]); bv1[i + 4] = f2bf(y[i]); }
        acc[0][0] = __builtin_amdgcn_mfma_f32_16x16x32_bf16(av0, bv0, acc[0][0], 0, 0, 0);
        acc[0][1] = __builtin_amdgcn_mfma_f32_16x16x32_bf16(av0, bv1, acc[0][1], 0, 0, 0);
        acc[1][0] = __builtin_amdgcn_mfma_f32_16x16x32_bf16(av1, bv0, acc[1][0], 0, 0, 0);
        acc[1][1] = __builtin_amdgcn_mfma_f32_16x16x32_bf16(av1, bv1, acc[1][1], 0, 0, 0);
    }
#pragma unroll
    for (int mf = 0; mf < 2; mf++) {
        int row0 = m0 + mf * 16 + (lane >> 4) * 4;
#pragma unroll
        for (int nf = 0; nf < 2; nf++) {
            int col = n0 + nf * 16 + l15;
            float bval = bias[col];
#pragma unroll
            for (int r = 0; r < 4; r++) {
                int row = row0 + r;
                if (row < M) C[(size_t)row * Dn + col] = acc[mf][nf][r] + bval;
            }
        }
    }
}

// ---------------------------------------------------------------- bf16 MFMA GEMM: C[M,1024] = A_bf[M,1024] @ B_bf[1024,1024]^T + bias
__global__ __launch_bounds__(256) void wgemm_mfma(const short* __restrict__ Abf,
                                                  const short* __restrict__ Bbf,
                                                  const float* __restrict__ bias,
                                                  float* __restrict__ C, int M) {
    int wave = threadIdx.x >> 6, lane = threadIdx.x & 63;
    int m0 = blockIdx.x * 64 + (wave >> 1) * 32;
    int n0 = blockIdx.y * 64 + (wave & 1) * 32;
    int koff = (lane >> 4) * 8;
    f32x4 acc[2][2] = {};
    int ra0 = min(m0 + (lane & 15), M - 1);
    int ra1 = min(m0 + 16 + (lane & 15), M - 1);
    const short* a0p = Abf + (size_t)ra0 * Dn + koff;
    const short* a1p = Abf + (size_t)ra1 * Dn + koff;
    const short* b0p = Bbf + (size_t)(n0 + (lane & 15)) * Dn + koff;
    const short* b1p = Bbf + (size_t)(n0 + 16 + (lane & 15)) * Dn + koff;
    for (int k0 = 0; k0 < Dn; k0 += 32) {
        short8 av0 = *(const short8*)(a0p + k0);
        short8 av1 = *(const short8*)(a1p + k0);
        short8 bv0 = *(const short8*)(b0p + k0);
        short8 bv1 = *(const short8*)(b1p + k0);
        acc[0][0] = __builtin_amdgcn_mfma_f32_16x16x32_bf16(av0, bv0, acc[0][0], 0, 0, 0);
        acc[0][1] = __builtin_amdgcn_mfma_f32_16x16x32_bf16(av0, bv1, acc[0][1], 0, 0, 0);
        acc[1][0] = __builtin_amdgcn_mfma_f32_16x16x32_bf16(av1, bv0, acc[1][0], 0, 0, 0);
        acc[1][1] = __builtin_amdgcn_mfma_f32_16x16x32_bf16(av1, bv1, acc[1][1], 0, 0, 0);
    }
#pragma unroll
    for (int mf = 0; mf < 2; mf++) {
        int row0 = m0 + mf * 16 + (lane >> 4) * 4;
#pragma unroll
        for (int nf = 0; nf < 2; nf++) {
            int col = n0 + nf * 16 + (lane & 15);
            float bval = bias[col];
#pragma unroll
            for (int r = 0; r < 4; r++) {
                int row = row0 + r;
                if (row < M) C[(size_t)row * Dn + col] = acc[mf][nf][r] + bval;
            }
        }
    }
}

// ---------------------------------------------------------------- block sum helper
__device__ __forceinline__ float block_sum(float v, float* red) {
    int tid = threadIdx.x;
    red[tid] = v;
    __syncthreads();
    for (int off = 128; off > 0; off >>= 1) {
        if (tid < off) red[tid] += red[tid + off];
        __syncthreads();
    }
    float r = red[0];
    __syncthreads();
    return r;
}

// ---------------------------------------------------------------- build summary row + LN_pma + LN_v / LN_g (bf16 out)
__global__ void summary_ln_kernel(const float* __restrict__ hidden,
                                  const float* __restrict__ queries,
                                  const float* __restrict__ pooled,
                                  const int* __restrict__ rsrc,
                                  const float* __restrict__ gpma, const float* __restrict__ bpma,
                                  const float* __restrict__ gv, const float* __restrict__ bv,
                                  const float* __restrict__ gg, const float* __restrict__ bg,
                                  short* __restrict__ lnv, short* __restrict__ lng) {
    __shared__ float red[256];
    int b = blockIdx.x, t = blockIdx.y, tid = threadIdx.x;
    float x[4];
    if (t == 0) {
#pragma unroll
        for (int i = 0; i < 4; i++)
            x[i] = hidden[(size_t)b * Sn * Dn + tid + i * 256];
    } else if (t < 1 + Pn) {
        int p = t - 1;
#pragma unroll
        for (int i = 0; i < 4; i++) {
            int c = tid + i * 256;
            x[i] = queries[p * Dn + c] + pooled[((size_t)b * Pn + p) * Dn + c];
        }
    } else {
        int src = rsrc[b * RECn + (t - 9)];
        if (src >= 0) {
#pragma unroll
            for (int i = 0; i < 4; i++)
                x[i] = hidden[((size_t)b * Sn + src) * Dn + tid + i * 256];
        } else {
#pragma unroll
            for (int i = 0; i < 4; i++) x[i] = 0.0f;
        }
    }
    if (t >= 1 && t < 1 + Pn) {
        float mu = block_sum(x[0] + x[1] + x[2] + x[3], red) * (1.0f / Dn);
        float d2 = 0.0f;
#pragma unroll
        for (int i = 0; i < 4; i++) { float d = x[i] - mu; d2 += d * d; }
        float inv = rsqrtf(block_sum(d2, red) * (1.0f / Dn) + 1e-5f);
#pragma unroll
        for (int i = 0; i < 4; i++) {
            int c = tid + i * 256;
            x[i] = (x[i] - mu) * inv * gpma[c] + bpma[c];
        }
    }
    float mu = block_sum(x[0] + x[1] + x[2] + x[3], red) * (1.0f / Dn);
    float d2 = 0.0f;
#pragma unroll
    for (int i = 0; i < 4; i++) { float d = x[i] - mu; d2 += d * d; }
    float inv = rsqrtf(block_sum(d2, red) * (1.0f / Dn) + 1e-5f);
    size_t row = (size_t)(b * Tn + t) * Dn;
#pragma unroll
    for (int i = 0; i < 4; i++) {
        int c = tid + i * 256;
        float xh = (x[i] - mu) * inv;
        lnv[row + c] = f2bf(xh * gv[c] + bv[c]);
        lng[row + c] = f2bf(xh * gg[c] + bg[c]);
    }
}

// ---------------------------------------------------------------- gated = sigmoid(c2) * silu(c1) * mask
__global__ void gated_kernel(const float* __restrict__ c1, const float* __restrict__ c2,
                             const float* __restrict__ maskf, float* __restrict__ out) {
    int gi = blockIdx.x * blockDim.x + threadIdx.x;
    int row = gi >> 10;
    float m = maskf[row];
    float a = c1[gi], g = c2[gi];
    float sv = a / (1.0f + expf(-a));
    float sg = 1.0f / (1.0f + expf(-g));
    out[gi] = sg * sv * m;
}

// ================================================================ launch
extern "C" void kernel_launch(void* const* d_in, const int* in_sizes, int n_in,
                              void* d_out, int out_size, void* d_ws, size_t ws_size,
                              hipStream_t stream) {
    const float* hidden = (const float*)d_in[0];
    const void* valid_raw = d_in[1];
    const float* queries = (const float*)d_in[2];
    const float* in_w = (const float*)d_in[3];
    const float* in_b = (const float*)d_in[4];
    const float* out_w = (const float*)d_in[5];
    const float* out_b = (const float*)d_in[6];
    const float* ln_pma_g = (const float*)d_in[7];
    const float* ln_pma_b = (const float*)d_in[8];
    const float* ln_v_g = (const float*)d_in[9];
    const float* ln_v_b = (const float*)d_in[10];
    const float* W_v = (const float*)d_in[11];
    const float* b_v = (const float*)d_in[12];
    const float* ln_g_g = (const float*)d_in[13];
    const float* ln_g_b = (const float*)d_in[14];
    const float* W_g = (const float*)d_in[15];
    const float* b_g = (const float*)d_in[16];

    float* ws = (float*)d_ws;
    float* out = (float*)d_out;

    // workspace layout (float offsets):
    float* SCp0    = ws;                         // 4,194,304 f (dead after softmax)
    float* SCp1    = ws + 4194304;               // 4,194,304 f (dead after softmax)
    short* attn_bf = (short*)(ws + 8388608);     // 4,194,304 shorts = 2,097,152 f
    float* Up0     = ws;                         // overlay dead SCp region
    float* Up1     = ws + 2097152;
    float* Up2     = ws + 4194304;
    float* Up3     = ws + 6291456;               // ends 8,388,608
    float* qbuf    = ws + 10485760;              // 8,192
    short* Amat_bf = (short*)(ws + 10493952);    // 65,536 f
    float* c0      = ws + 10559488;              // 256
    float* ctx     = ws + 10559744;              // 131,072
    float* pooled  = ws + 10690816;              // 131,072
    short* Wv_bf   = (short*)(ws + 10821888);    // 524,288 f
    short* Wg_bf   = (short*)(ws + 11346176);    // 524,288 f
    int*   ivals   = (int*)(ws + 11870464);
    int* totals = ivals;                         // 16
    int* rsrc = ivals + 16;                      // 1024
    int* flag = ivals + 16 + 1024;               // 16
    unsigned char* canon = (unsigned char*)(ivals + 16 + 1024 + 16); // 32768 B
    // post-ctx overlays (Up0..3 dead after ctx):
    short* lnv_bf = (short*)ws;
    short* lng_bf = (short*)(ws + 622592);
    float* c1 = ws + 1245184;
    float* c2 = ws + 2441216;                    // ends 3,637,248 < 8,388,608 OK
    float* maskf = out + (size_t)Bn * Tn * Dn;

    const int M2 = Bn * Tn; // 1168

    detect_mask_kernel<<<1, 256, 0, stream>>>((const unsigned char*)valid_raw, flag);
    canon_mask_kernel<<<(Bn * Sn) / 256, 256, 0, stream>>>(valid_raw, flag, canon);
    prep_kernel<<<Bn, 256, 0, stream>>>(canon, totals, rsrc, maskf);
    q_kernel<<<(Pn * Dn) / 4, 256, 0, stream>>>(queries, in_w, in_b, qbuf);
    A_kernel<<<dim3(Hn, 4), 256, 0, stream>>>(qbuf, in_w, in_b, Amat_bf, c0);
    wcvt_kernel<<<512, 256, 0, stream>>>(W_v, Wv_bf, Dn * Dn);
    wcvt_kernel<<<512, 256, 0, stream>>>(W_g, Wg_bf, Dn * Dn);
    scores_mfma<<<dim3(256, 2), 512, 0, stream>>>(hidden, Amat_bf, SCp0, SCp1);
    softmax_kernel<<<Bn * 128, 256, 0, stream>>>(SCp0, SCp1, c0, canon, attn_bf);
    U_mfma<<<dim3(8, Bn, 4), 512, 0, stream>>>(attn_bf, hidden, Up0, Up1, Up2, Up3);
    ctx_mfma<<<Bn * Hn, 64, 0, stream>>>(Up0, Up1, Up2, Up3, in_w, in_b, ctx);
    pooled_mfma<<<dim3(2, 16), 256, 0, stream>>>(ctx, out_w, out_b, pooled, Bn * Pn);
    summary_ln_kernel<<<dim3(Bn, Tn), 256, 0, stream>>>(hidden, queries, pooled, rsrc,
                                                        ln_pma_g, ln_pma_b, ln_v_g, ln_v_b,
                                                        ln_g_g, ln_g_b, lnv_bf, lng_bf);
    wgemm_mfma<<<dim3((M2 + 63) / 64, 16), 256, 0, stream>>>(lnv_bf, Wv_bf, b_v, c1, M2);
    wgemm_mfma<<<dim3((M2 + 63) / 64, 16), 256, 0, stream>>>(lng_bf, Wg_bf, b_g, c2, M2);
    gated_kernel<<<(Bn * Tn * Dn) / 256, 256, 0, stream>>>(c1, c2, maskf, out);
}